// Round 2
// baseline (502.210 us; speedup 1.0000x reference)
//
#include <hip/hip_runtime.h>
#include <hip/hip_cooperative_groups.h>
#include <math.h>

namespace cg = cooperative_groups;

#define BB 8
#define NN 2048
#define FF 128
#define CH 128        // chunks per batch
#define CHSZ 16       // NN / CH

// ===========================================================================
// FUSED cooperative kernel: all 5 phases in one dispatch, grid.sync between.
// grid = 256 blocks x 512 threads (1 block/CU on MI355X -> co-resident).
// Phase arithmetic matches the verified 5-kernel pipeline phase-for-phase
// (P3b's vector suffix uses a tree scan instead of serial walk: ulp-level).
// ===========================================================================

struct Params {
    const float* __restrict__ h;
    const float* __restrict__ W;
    const float* __restrict__ a;
    float* __restrict__ Wh;
    float* __restrict__ partial;
    float* __restrict__ s1;
    float* __restrict__ s2;
    float* __restrict__ ps;
    float* __restrict__ psuf;
    int*   __restrict__ idxs;
    int*   __restrict__ lo_arr;
    float* __restrict__ chunktot;
    float* __restrict__ chunku;
    float* __restrict__ chunksuf;
    float* __restrict__ chunkp;
    float* __restrict__ chunkpsuf;
    float* __restrict__ meanv;
    float* __restrict__ out;
};

union __align__(16) SMem {
    struct { float Wt[64][132]; float hs[64][65]; } p1;                       // ~49.3 KB
    struct { float ls[NN]; int part[8][64]; int lpart[8][64]; float wmax[8]; } p2;
    struct { float lt[4][132]; float lu[4][132]; float lp[CH]; } p3b;
};

__global__ __launch_bounds__(512) void fused(Params P) {
    __shared__ SMem sm;
    const int tid = threadIdx.x;
    const int blk = blockIdx.x;
    cg::grid_group grid = cg::this_grid();

    // -------------------------------------------------------------------
    // Phase 1 (== k1): Wh[b,n,g] = sum_f h[b,n,f]*W[g,f]; s1 = Wh.a1, s2 = Wh.a2
    // 64 rows/block, per-thread tile 8g x 2r. Identical math/order to k1_wh.
    // -------------------------------------------------------------------
    {
        const int row0 = blk * 64;
        const int gq = tid & 15;
        const int rq = tid >> 4;

        float acc[2][8];
#pragma unroll
        for (int r = 0; r < 2; ++r)
#pragma unroll
            for (int g = 0; g < 8; ++g) acc[r][g] = 0.f;

        for (int half = 0; half < 2; ++half) {
            __syncthreads();
            for (int idx = tid; idx < 64 * 128; idx += 512) {
                int g = idx >> 6, fl = idx & 63;
                sm.p1.Wt[fl][g] = P.W[g * 128 + half * 64 + fl];
            }
            for (int idx = tid; idx < 64 * 64; idx += 512) {
                int r = idx >> 6, fl = idx & 63;
                sm.p1.hs[r][fl] = P.h[(row0 + r) * 128 + half * 64 + fl];
            }
            __syncthreads();
            for (int fl = 0; fl < 64; ++fl) {
                float4 w0 = *(const float4*)&sm.p1.Wt[fl][gq * 8];
                float4 w1 = *(const float4*)&sm.p1.Wt[fl][gq * 8 + 4];
                float h0 = sm.p1.hs[rq * 2 + 0][fl];
                float h1 = sm.p1.hs[rq * 2 + 1][fl];
                acc[0][0] += h0 * w0.x; acc[0][1] += h0 * w0.y;
                acc[0][2] += h0 * w0.z; acc[0][3] += h0 * w0.w;
                acc[0][4] += h0 * w1.x; acc[0][5] += h0 * w1.y;
                acc[0][6] += h0 * w1.z; acc[0][7] += h0 * w1.w;
                acc[1][0] += h1 * w0.x; acc[1][1] += h1 * w0.y;
                acc[1][2] += h1 * w0.z; acc[1][3] += h1 * w0.w;
                acc[1][4] += h1 * w1.x; acc[1][5] += h1 * w1.y;
                acc[1][6] += h1 * w1.z; acc[1][7] += h1 * w1.w;
            }
        }

        float a1v[8], a2v[8];
#pragma unroll
        for (int g = 0; g < 8; ++g) {
            a1v[g] = P.a[gq * 8 + g];
            a2v[g] = P.a[128 + gq * 8 + g];
        }
#pragma unroll
        for (int r = 0; r < 2; ++r) {
            int row = row0 + rq * 2 + r;
            *(float4*)&P.Wh[row * 128 + gq * 8] =
                make_float4(acc[r][0], acc[r][1], acc[r][2], acc[r][3]);
            *(float4*)&P.Wh[row * 128 + gq * 8 + 4] =
                make_float4(acc[r][4], acc[r][5], acc[r][6], acc[r][7]);
            float p1 = 0.f, p2 = 0.f;
#pragma unroll
            for (int g = 0; g < 8; ++g) {
                p1 += acc[r][g] * a1v[g];
                p2 += acc[r][g] * a2v[g];
            }
#pragma unroll
            for (int s = 1; s < 16; s <<= 1) {
                p1 += __shfl_xor(p1, s, 64);
                p2 += __shfl_xor(p2, s, 64);
            }
            if (gq == 0) { P.s1[row] = p1; P.s2[row] = p2; }
        }
    }
    __threadfence();
    grid.sync();

    // -------------------------------------------------------------------
    // Phase 2 (== k2 @512thr): stable rank by s2 + exp + threshold count.
    // block = (b, seg of 64 j's); 8 waves each scan 256 keys.
    // Integer counts identical; M identical (max is order-free).
    // -------------------------------------------------------------------
    {
        const int b = blk >> 5;
        const int seg = blk & 31;
        const int base = b * NN;
        float* ls = sm.p2.ls;
        float4* ls4 = (float4*)ls;
        const float4* g4 = (const float4*)(P.s2 + base);
        float m = -INFINITY;
        {
            float4 v4 = g4[tid];           // 512 float4 = 2048 keys
            ls4[tid] = v4;
            m = fmaxf(fmaxf(v4.x, v4.y), fmaxf(v4.z, v4.w));
        }
#pragma unroll
        for (int s = 1; s < 64; s <<= 1) m = fmaxf(m, __shfl_xor(m, s, 64));
        if ((tid & 63) == 0) sm.p2.wmax[tid >> 6] = m;
        __syncthreads();
        float M = sm.p2.wmax[0];
#pragma unroll
        for (int i = 1; i < 8; ++i) M = fmaxf(M, sm.p2.wmax[i]);
        const int jj = tid & 63;
        const int w  = tid >> 6;
        const int j  = seg * 64 + jj;
        const float v = ls[j];
        const float s1v = P.s1[base + j];
        int rank = 0, cnt = 0;
#pragma unroll 8
        for (int q = 0; q < 64; ++q) {
            float4 kv = ls4[w * 64 + q];   // wave-broadcast, conflict-free
            int kg = w * 256 + q * 4;
            rank += (kv.x < v) | ((kv.x == v) & (kg + 0 < j));
            rank += (kv.y < v) | ((kv.y == v) & (kg + 1 < j));
            rank += (kv.z < v) | ((kv.z == v) & (kg + 2 < j));
            rank += (kv.w < v) | ((kv.w == v) & (kg + 3 < j));
            cnt += (s1v + kv.x <= 0.f);
            cnt += (s1v + kv.y <= 0.f);
            cnt += (s1v + kv.z <= 0.f);
            cnt += (s1v + kv.w <= 0.f);
        }
        sm.p2.part[w][jj] = rank;
        sm.p2.lpart[w][jj] = cnt;
        __syncthreads();
        if (tid < 64) {
            int r = 0, lo = 0;
#pragma unroll
            for (int ww = 0; ww < 8; ++ww) {
                r  += sm.p2.part[ww][tid];
                lo += sm.p2.lpart[ww][tid];
            }
            int jg = seg * 64 + tid;
            float vv = ls[jg];
            P.idxs[base + r] = jg;
            P.ps[base + r] = expf(vv - M);
            P.lo_arr[base + jg] = lo;
        }
    }
    __threadfence();
    grid.sync();

    // -------------------------------------------------------------------
    // Phase 3 (== k3): within-chunk inclusive suffix of p*Wh (4 chunks/block,
    // thread = (chunk-quadrant, f)). Same serial descending order per chunk.
    // -------------------------------------------------------------------
    {
        const int cq = tid >> 7;           // 0..3
        const int f  = tid & 127;
        const int cg_ = blk * 4 + cq;      // global chunk 0..1023
        const int b = cg_ >> 7;
        const int c = cg_ & 127;
        const int base = b * NN;
        float acc = 0.f, accu = 0.f, pacc = 0.f;
#pragma unroll
        for (int tt = CHSZ - 1; tt >= 0; --tt) {
            int r = c * CHSZ + tt;
            int jj2 = P.idxs[base + r];
            float pv = P.ps[base + r];
            float wv = P.Wh[(base + jj2) * 128 + f];
            acc += pv * wv;
            accu += wv;
            pacc += pv;
            P.partial[(base + r) * 128 + f] = acc;
            if (f == 0) P.psuf[base + r] = pacc;
        }
        P.chunktot[(b * CH + c) * 128 + f] = acc;
        P.chunku[(b * CH + c) * 128 + f] = accu;
        if (f == 0) P.chunkp[b * CH + c] = pacc;
    }
    __threadfence();
    grid.sync();

    // -------------------------------------------------------------------
    // Phase 3b (parallelized k3b): block = (b, group of 4 f's); threads =
    // (c, f_local). Tree suffix-scan over 128 chunks (7 Hillis-Steele steps).
    // chunkpsuf scan structure identical to the original; lt/lu order is
    // tree instead of serial (ulp-level difference only).
    // -------------------------------------------------------------------
    {
        const int b  = blk >> 5;
        const int fg = blk & 31;
        const int c  = tid >> 2;           // 0..127
        const int fl = tid & 3;
        const int f  = fg * 4 + fl;
        sm.p3b.lt[fl][c] = P.chunktot[(b * CH + c) * 128 + f];
        sm.p3b.lu[fl][c] = P.chunku[(b * CH + c) * 128 + f];
        if (tid < CH) sm.p3b.lp[tid] = P.chunkp[b * CH + tid];
        __syncthreads();
#pragma unroll
        for (int s = 1; s < CH; s <<= 1) {
            float av = 0.f, au = 0.f, ap = 0.f;
            if (c + s < CH) { av = sm.p3b.lt[fl][c + s]; au = sm.p3b.lu[fl][c + s]; }
            if (tid < CH && tid + s < CH) ap = sm.p3b.lp[tid + s];
            __syncthreads();
            sm.p3b.lt[fl][c] += av;
            sm.p3b.lu[fl][c] += au;
            if (tid < CH) sm.p3b.lp[tid] += ap;
            __syncthreads();
        }
        // exclusive suffix = inclusive at c+1
        P.chunksuf[(b * CH + c) * 128 + f] =
            (c < CH - 1) ? sm.p3b.lt[fl][c + 1] : 0.f;
        if (fg == 0 && fl == 0)
            P.chunkpsuf[b * CH + c] = (c < CH - 1) ? sm.p3b.lp[c + 1] : 0.f;
        if (c == 0)
            P.meanv[b * 128 + f] = sm.p3b.lu[fl][0] * (1.f / (float)NN);
    }
    __threadfence();
    grid.sync();

    // -------------------------------------------------------------------
    // Phase 4 (== k4): combine. 64 rows/block via 4 passes of 16 rows.
    // -------------------------------------------------------------------
    {
#pragma unroll
        for (int pass = 0; pass < 4; ++pass) {
            const int rowg = blk * 64 + pass * 16 + (tid >> 5);
            const int fq = (tid & 31) * 4;
            const int b = rowg >> 11;      // / NN
            const int base = b * NN;
            const int lo = P.lo_arr[rowg];
            float4 v;
            if (lo == NN) {
                v = *(const float4*)&P.meanv[b * 128 + fq];
            } else {
                const int c = lo >> 4;     // / CHSZ
                float4 pp = *(const float4*)&P.partial[(base + lo) * 128 + fq];
                float4 cs = *(const float4*)&P.chunksuf[(b * CH + c) * 128 + fq];
                float den = P.psuf[base + lo] + P.chunkpsuf[b * CH + c];
                v.x = (pp.x + cs.x) / den;
                v.y = (pp.y + cs.y) / den;
                v.z = (pp.z + cs.z) / den;
                v.w = (pp.w + cs.w) / den;
            }
            v.x = (v.x > 0.f) ? v.x : expm1f(v.x);
            v.y = (v.y > 0.f) ? v.y : expm1f(v.y);
            v.z = (v.z > 0.f) ? v.z : expm1f(v.z);
            v.w = (v.w > 0.f) ? v.w : expm1f(v.w);
            *(float4*)&P.out[rowg * 128 + fq] = v;
        }
    }
}

// ===========================================================================
// Fallback: the previous verified 5-kernel pipeline (used only if the
// cooperative launch is unsupported/rejected).
// ===========================================================================

__global__ __launch_bounds__(512) void k1_wh(
        const float* __restrict__ h, const float* __restrict__ W,
        const float* __restrict__ a, float* __restrict__ Wh,
        float* __restrict__ s1, float* __restrict__ s2) {
    __shared__ __align__(16) float Wt[64][132];
    __shared__ float hs[64][65];
    const int tid = threadIdx.x;
    const int row0 = blockIdx.x * 64;
    const int gq = tid & 15;
    const int rq = tid >> 4;

    float acc[2][8];
#pragma unroll
    for (int r = 0; r < 2; ++r)
#pragma unroll
        for (int g = 0; g < 8; ++g) acc[r][g] = 0.f;

    for (int half = 0; half < 2; ++half) {
        __syncthreads();
        for (int idx = tid; idx < 64 * 128; idx += 512) {
            int g = idx >> 6, fl = idx & 63;
            Wt[fl][g] = W[g * 128 + half * 64 + fl];
        }
        for (int idx = tid; idx < 64 * 64; idx += 512) {
            int r = idx >> 6, fl = idx & 63;
            hs[r][fl] = h[(row0 + r) * 128 + half * 64 + fl];
        }
        __syncthreads();
        for (int fl = 0; fl < 64; ++fl) {
            float4 w0 = *(const float4*)&Wt[fl][gq * 8];
            float4 w1 = *(const float4*)&Wt[fl][gq * 8 + 4];
            float h0 = hs[rq * 2 + 0][fl];
            float h1 = hs[rq * 2 + 1][fl];
            acc[0][0] += h0 * w0.x; acc[0][1] += h0 * w0.y;
            acc[0][2] += h0 * w0.z; acc[0][3] += h0 * w0.w;
            acc[0][4] += h0 * w1.x; acc[0][5] += h0 * w1.y;
            acc[0][6] += h0 * w1.z; acc[0][7] += h0 * w1.w;
            acc[1][0] += h1 * w0.x; acc[1][1] += h1 * w0.y;
            acc[1][2] += h1 * w0.z; acc[1][3] += h1 * w0.w;
            acc[1][4] += h1 * w1.x; acc[1][5] += h1 * w1.y;
            acc[1][6] += h1 * w1.z; acc[1][7] += h1 * w1.w;
        }
    }

    float a1v[8], a2v[8];
#pragma unroll
    for (int g = 0; g < 8; ++g) {
        a1v[g] = a[gq * 8 + g];
        a2v[g] = a[128 + gq * 8 + g];
    }
#pragma unroll
    for (int r = 0; r < 2; ++r) {
        int row = row0 + rq * 2 + r;
        *(float4*)&Wh[row * 128 + gq * 8] =
            make_float4(acc[r][0], acc[r][1], acc[r][2], acc[r][3]);
        *(float4*)&Wh[row * 128 + gq * 8 + 4] =
            make_float4(acc[r][4], acc[r][5], acc[r][6], acc[r][7]);
        float p1 = 0.f, p2 = 0.f;
#pragma unroll
        for (int g = 0; g < 8; ++g) {
            p1 += acc[r][g] * a1v[g];
            p2 += acc[r][g] * a2v[g];
        }
#pragma unroll
        for (int s = 1; s < 16; s <<= 1) {
            p1 += __shfl_xor(p1, s, 64);
            p2 += __shfl_xor(p2, s, 64);
        }
        if (gq == 0) { s1[row] = p1; s2[row] = p2; }
    }
}

__global__ __launch_bounds__(256) void k2_rank(
        const float* __restrict__ s2, const float* __restrict__ s1,
        int* __restrict__ idxs, float* __restrict__ ps,
        int* __restrict__ lo_arr) {
    __shared__ __align__(16) float ls[NN];
    __shared__ int part[4][64];
    __shared__ int lpart[4][64];
    __shared__ float wmax[4];
    const int t = threadIdx.x;
    const int blk = blockIdx.x;
    const int b = blk >> 5;
    const int seg = blk & 31;
    const int base = b * NN;
    float4* ls4 = (float4*)ls;
    const float4* g4 = (const float4*)(s2 + base);
    float m = -INFINITY;
    for (int i = t; i < NN / 4; i += 256) {
        float4 v4 = g4[i];
        ls4[i] = v4;
        m = fmaxf(m, fmaxf(fmaxf(v4.x, v4.y), fmaxf(v4.z, v4.w)));
    }
#pragma unroll
    for (int s = 1; s < 64; s <<= 1) m = fmaxf(m, __shfl_xor(m, s, 64));
    if ((t & 63) == 0) wmax[t >> 6] = m;
    __syncthreads();
    const float M = fmaxf(fmaxf(wmax[0], wmax[1]), fmaxf(wmax[2], wmax[3]));
    const int jj = t & 63;
    const int w  = t >> 6;
    const int j  = seg * 64 + jj;
    const float v = ls[j];
    const float s1v = s1[base + j];
    int rank = 0, cnt = 0;
#pragma unroll 8
    for (int q = 0; q < 128; ++q) {
        float4 kv = ls4[w * 128 + q];
        int kg = w * 512 + q * 4;
        rank += (kv.x < v) | ((kv.x == v) & (kg + 0 < j));
        rank += (kv.y < v) | ((kv.y == v) & (kg + 1 < j));
        rank += (kv.z < v) | ((kv.z == v) & (kg + 2 < j));
        rank += (kv.w < v) | ((kv.w == v) & (kg + 3 < j));
        cnt += (s1v + kv.x <= 0.f);
        cnt += (s1v + kv.y <= 0.f);
        cnt += (s1v + kv.z <= 0.f);
        cnt += (s1v + kv.w <= 0.f);
    }
    part[w][jj] = rank;
    lpart[w][jj] = cnt;
    __syncthreads();
    if (t < 64) {
        int r = part[0][t] + part[1][t] + part[2][t] + part[3][t];
        int jg = seg * 64 + t;
        float vv = ls[jg];
        idxs[base + r] = jg;
        ps[base + r] = expf(vv - M);
        lo_arr[base + jg] = lpart[0][t] + lpart[1][t] + lpart[2][t] + lpart[3][t];
    }
}

__global__ __launch_bounds__(128) void k3_scan(
        const float* __restrict__ Wh, const int* __restrict__ idxs,
        const float* __restrict__ ps,
        float* __restrict__ partial, float* __restrict__ psuf,
        float* __restrict__ chunktot, float* __restrict__ chunku,
        float* __restrict__ chunkp) {
    const int blk = blockIdx.x;
    const int b = blk >> 7, c = blk & 127;
    const int base = b * NN;
    const int f = threadIdx.x;
    float acc = 0.f, accu = 0.f, pacc = 0.f;
#pragma unroll
    for (int tt = CHSZ - 1; tt >= 0; --tt) {
        int r = c * CHSZ + tt;
        int jj = idxs[base + r];
        float pv = ps[base + r];
        float w = Wh[(base + jj) * 128 + f];
        acc += pv * w;
        accu += w;
        pacc += pv;
        partial[(base + r) * 128 + f] = acc;
        if (f == 0) psuf[base + r] = pacc;
    }
    chunktot[(b * CH + c) * 128 + f] = acc;
    chunku[(b * CH + c) * 128 + f] = accu;
    if (f == 0) chunkp[b * CH + c] = pacc;
}

__global__ __launch_bounds__(128) void k3b_chunksuf(
        const float* __restrict__ chunktot, const float* __restrict__ chunku,
        const float* __restrict__ chunkp,
        float* __restrict__ chunksuf, float* __restrict__ chunkpsuf,
        float* __restrict__ meanv) {
    __shared__ float lt[CH][128];
    __shared__ float lp[CH];
    const int b = blockIdx.x;
    const int f = threadIdx.x;
    float tu = 0.f;
#pragma unroll 4
    for (int c = 0; c < CH; ++c) {
        lt[c][f] = chunktot[(b * CH + c) * 128 + f];
        tu += chunku[(b * CH + c) * 128 + f];
    }
    lp[f] = chunkp[b * CH + f];
    __syncthreads();
#pragma unroll
    for (int s = 1; s < CH; s <<= 1) {
        float add = (f + s < CH) ? lp[f + s] : 0.f;
        __syncthreads();
        lp[f] += add;
        __syncthreads();
    }
    chunkpsuf[b * CH + f] = (f < CH - 1) ? lp[f + 1] : 0.f;
    float acc = 0.f;
#pragma unroll 4
    for (int c = CH - 1; c >= 0; --c) {
        chunksuf[(b * CH + c) * 128 + f] = acc;
        acc += lt[c][f];
    }
    meanv[b * 128 + f] = tu * (1.f / (float)NN);
}

__global__ __launch_bounds__(256) void k4_out(
        const int* __restrict__ lo_arr, const float* __restrict__ psuf,
        const float* __restrict__ chunkpsuf, const float* __restrict__ partial,
        const float* __restrict__ chunksuf, const float* __restrict__ meanv,
        float* __restrict__ out) {
    const int tid = threadIdx.x;
    const int rowg = blockIdx.x * 8 + (tid >> 5);
    const int fq = (tid & 31) * 4;
    const int b = rowg >> 11;
    const int base = b * NN;
    const int lo = lo_arr[rowg];
    float4 v;
    if (lo == NN) {
        v = *(const float4*)&meanv[b * 128 + fq];
    } else {
        const int c = lo >> 4;
        float4 pp = *(const float4*)&partial[(base + lo) * 128 + fq];
        float4 cs = *(const float4*)&chunksuf[(b * CH + c) * 128 + fq];
        float den = psuf[base + lo] + chunkpsuf[b * CH + c];
        v.x = (pp.x + cs.x) / den;
        v.y = (pp.y + cs.y) / den;
        v.z = (pp.z + cs.z) / den;
        v.w = (pp.w + cs.w) / den;
    }
    v.x = (v.x > 0.f) ? v.x : expm1f(v.x);
    v.y = (v.y > 0.f) ? v.y : expm1f(v.y);
    v.z = (v.z > 0.f) ? v.z : expm1f(v.z);
    v.w = (v.w > 0.f) ? v.w : expm1f(v.w);
    *(float4*)&out[rowg * 128 + fq] = v;
}

// ---------------------------------------------------------------------------
extern "C" void kernel_launch(void* const* d_in, const int* in_sizes, int n_in,
                              void* d_out, int out_size, void* d_ws, size_t ws_size,
                              hipStream_t stream) {
    (void)in_sizes; (void)n_in; (void)out_size; (void)ws_size;
    const float* h = (const float*)d_in[0];
    const float* W = (const float*)d_in[1];
    const float* a = (const float*)d_in[2];
    float* out = (float*)d_out;

    float* Wh       = (float*)d_ws;          // B*N*F = 2,097,152
    float* partial  = Wh + 2097152;          // B*N*F
    float* s1       = partial + 2097152;     // 16384
    float* s2       = s1 + 16384;
    float* ps       = s2 + 16384;
    float* psuf     = ps + 16384;
    int*   idxs     = (int*)(psuf + 16384);
    int*   lo_arr   = idxs + 16384;
    float* chunktot = (float*)(lo_arr + 16384); // B*CH*F = 131072
    float* chunku   = chunktot + 131072;
    float* chunksuf = chunku + 131072;
    float* chunkp   = chunksuf + 131072;     // B*CH = 1024
    float* chunkpsuf= chunkp + 1024;
    float* meanv    = chunkpsuf + 1024;

    // Cooperative-launch support: queried once, host-side, capture-safe.
    static int coop_support = -1;
    if (coop_support < 0) {
        int dev = 0, v = 0;
        (void)hipGetDevice(&dev);
        if (hipDeviceGetAttribute(&v, hipDeviceAttributeCooperativeLaunch, dev)
                != hipSuccess) v = 0;
        coop_support = v;
    }

    bool launched = false;
    if (coop_support) {
        Params P;
        P.h = h; P.W = W; P.a = a;
        P.Wh = Wh; P.partial = partial; P.s1 = s1; P.s2 = s2;
        P.ps = ps; P.psuf = psuf; P.idxs = idxs; P.lo_arr = lo_arr;
        P.chunktot = chunktot; P.chunku = chunku; P.chunksuf = chunksuf;
        P.chunkp = chunkp; P.chunkpsuf = chunkpsuf; P.meanv = meanv;
        P.out = out;
        void* args[] = { (void*)&P };
        hipError_t err = hipLaunchCooperativeKernel(
            (const void*)fused, dim3(256), dim3(512), args, 0, stream);
        if (err == hipSuccess) {
            launched = true;
        } else {
            (void)hipGetLastError();   // clear sticky error, fall back
        }
    }

    if (!launched) {
        k1_wh<<<BB * NN / 64, 512, 0, stream>>>(h, W, a, Wh, s1, s2);
        k2_rank<<<BB * 32, 256, 0, stream>>>(s2, s1, idxs, ps, lo_arr);
        k3_scan<<<BB * CH, 128, 0, stream>>>(Wh, idxs, ps, partial, psuf,
                                             chunktot, chunku, chunkp);
        k3b_chunksuf<<<BB, 128, 0, stream>>>(chunktot, chunku, chunkp,
                                             chunksuf, chunkpsuf, meanv);
        k4_out<<<BB * NN / 8, 256, 0, stream>>>(lo_arr, psuf, chunkpsuf,
                                                partial, chunksuf, meanv, out);
    }
}

// Round 3
// 188.170 us; speedup vs baseline: 2.6689x; 2.6689x over previous
//
#include <hip/hip_runtime.h>
#include <math.h>

#define BB 8
#define NN 2048
#define FF 128
#define CH 128        // chunks per batch
#define CHSZ 16       // NN / CH

// ---------------------------------------------------------------------------
// Kernel 1: Wh[b,n,g] = sum_f h[b,n,f] * W[g,f];  s1 = Wh·a[:F], s2 = Wh·a[F:]
// block = 512 threads, 64 rows/block, per-thread tile 8g x 2r. (verified)
// ---------------------------------------------------------------------------
__global__ __launch_bounds__(512) void k1_wh(
        const float* __restrict__ h, const float* __restrict__ W,
        const float* __restrict__ a, float* __restrict__ Wh,
        float* __restrict__ s1, float* __restrict__ s2) {
    __shared__ __align__(16) float Wt[64][132];  // Wt[f_local][g], padded
    __shared__ float hs[64][65];                 // hs[r][f_local], padded
    const int tid = threadIdx.x;
    const int row0 = blockIdx.x * 64;            // global row = b*NN + i
    const int gq = tid & 15;                     // g = gq*8 .. gq*8+7
    const int rq = tid >> 4;                     // rows rq*2, rq*2+1

    float acc[2][8];
#pragma unroll
    for (int r = 0; r < 2; ++r)
#pragma unroll
        for (int g = 0; g < 8; ++g) acc[r][g] = 0.f;

    for (int half = 0; half < 2; ++half) {
        __syncthreads();
        for (int idx = tid; idx < 64 * 128; idx += 512) {
            int g = idx >> 6, fl = idx & 63;
            Wt[fl][g] = W[g * 128 + half * 64 + fl];
        }
        for (int idx = tid; idx < 64 * 64; idx += 512) {
            int r = idx >> 6, fl = idx & 63;
            hs[r][fl] = h[(row0 + r) * 128 + half * 64 + fl];
        }
        __syncthreads();
        for (int fl = 0; fl < 64; ++fl) {
            float4 w0 = *(const float4*)&Wt[fl][gq * 8];
            float4 w1 = *(const float4*)&Wt[fl][gq * 8 + 4];
            float h0 = hs[rq * 2 + 0][fl];
            float h1 = hs[rq * 2 + 1][fl];
            acc[0][0] += h0 * w0.x; acc[0][1] += h0 * w0.y;
            acc[0][2] += h0 * w0.z; acc[0][3] += h0 * w0.w;
            acc[0][4] += h0 * w1.x; acc[0][5] += h0 * w1.y;
            acc[0][6] += h0 * w1.z; acc[0][7] += h0 * w1.w;
            acc[1][0] += h1 * w0.x; acc[1][1] += h1 * w0.y;
            acc[1][2] += h1 * w0.z; acc[1][3] += h1 * w0.w;
            acc[1][4] += h1 * w1.x; acc[1][5] += h1 * w1.y;
            acc[1][6] += h1 * w1.z; acc[1][7] += h1 * w1.w;
        }
    }

    float a1v[8], a2v[8];
#pragma unroll
    for (int g = 0; g < 8; ++g) {
        a1v[g] = a[gq * 8 + g];
        a2v[g] = a[128 + gq * 8 + g];
    }
#pragma unroll
    for (int r = 0; r < 2; ++r) {
        int row = row0 + rq * 2 + r;
        *(float4*)&Wh[row * 128 + gq * 8] =
            make_float4(acc[r][0], acc[r][1], acc[r][2], acc[r][3]);
        *(float4*)&Wh[row * 128 + gq * 8 + 4] =
            make_float4(acc[r][4], acc[r][5], acc[r][6], acc[r][7]);
        float p1 = 0.f, p2 = 0.f;
#pragma unroll
        for (int g = 0; g < 8; ++g) {
            p1 += acc[r][g] * a1v[g];
            p2 += acc[r][g] * a2v[g];
        }
#pragma unroll
        for (int s = 1; s < 16; s <<= 1) {
            p1 += __shfl_xor(p1, s, 64);
            p2 += __shfl_xor(p2, s, 64);
        }
        if (gq == 0) { s1[row] = p1; s2[row] = p2; }
    }
}

// ---------------------------------------------------------------------------
// Kernel 2 (512-thread variant, logic verified in round-2 fused P2):
// stable rank by s2 + exp + threshold count. grid = B*32, block = 512.
// 8 waves each scan 256 keys; integer counts identical to baseline.
// ---------------------------------------------------------------------------
__global__ __launch_bounds__(512) void k2_rank(
        const float* __restrict__ s2, const float* __restrict__ s1,
        int* __restrict__ idxs, float* __restrict__ ps,
        int* __restrict__ lo_arr) {
    __shared__ __align__(16) float ls[NN];
    __shared__ int part[8][64];
    __shared__ int lpart[8][64];
    __shared__ float wmax[8];
    const int t = threadIdx.x;
    const int blk = blockIdx.x;
    const int b = blk >> 5;              // 32 segs per batch
    const int seg = blk & 31;
    const int base = b * NN;
    float4* ls4 = (float4*)ls;
    const float4* g4 = (const float4*)(s2 + base);
    float m;
    {
        float4 v4 = g4[t];               // 512 float4 = 2048 keys
        ls4[t] = v4;
        m = fmaxf(fmaxf(v4.x, v4.y), fmaxf(v4.z, v4.w));
    }
#pragma unroll
    for (int s = 1; s < 64; s <<= 1) m = fmaxf(m, __shfl_xor(m, s, 64));
    if ((t & 63) == 0) wmax[t >> 6] = m;
    __syncthreads();
    float M = wmax[0];
#pragma unroll
    for (int i = 1; i < 8; ++i) M = fmaxf(M, wmax[i]);
    const int jj = t & 63;
    const int w  = t >> 6;
    const int j  = seg * 64 + jj;        // global j within batch
    const float v = ls[j];
    const float s1v = s1[base + j];
    int rank = 0, cnt = 0;
#pragma unroll 8
    for (int q = 0; q < 64; ++q) {
        float4 kv = ls4[w * 64 + q];     // wave-broadcast, conflict-free
        int kg = w * 256 + q * 4;
        rank += (kv.x < v) | ((kv.x == v) & (kg + 0 < j));
        rank += (kv.y < v) | ((kv.y == v) & (kg + 1 < j));
        rank += (kv.z < v) | ((kv.z == v) & (kg + 2 < j));
        rank += (kv.w < v) | ((kv.w == v) & (kg + 3 < j));
        cnt += (s1v + kv.x <= 0.f);
        cnt += (s1v + kv.y <= 0.f);
        cnt += (s1v + kv.z <= 0.f);
        cnt += (s1v + kv.w <= 0.f);
    }
    part[w][jj] = rank;
    lpart[w][jj] = cnt;
    __syncthreads();
    if (t < 64) {
        int r = 0, lo = 0;
#pragma unroll
        for (int ww = 0; ww < 8; ++ww) {
            r  += part[ww][t];
            lo += lpart[ww][t];
        }
        int jg = seg * 64 + t;
        float vv = ls[jg];
        idxs[base + r] = jg;
        ps[base + r] = expf(vv - M);
        lo_arr[base + jg] = lo;
    }
}

// ---------------------------------------------------------------------------
// Kernel 3: within-chunk inclusive suffix of p[r]*Wh[idx[r],:] (-> partial),
// p[r] (-> psuf, f==0), plus chunk totals and unweighted sums. (verified)
// grid = B*CH blocks, 128 threads (f). Descending accumulation order.
// ---------------------------------------------------------------------------
__global__ __launch_bounds__(128) void k3_scan(
        const float* __restrict__ Wh, const int* __restrict__ idxs,
        const float* __restrict__ ps,
        float* __restrict__ partial, float* __restrict__ psuf,
        float* __restrict__ chunktot, float* __restrict__ chunku,
        float* __restrict__ chunkp) {
    const int blk = blockIdx.x;
    const int b = blk >> 7, c = blk & 127;
    const int base = b * NN;
    const int f = threadIdx.x;
    float acc = 0.f, accu = 0.f, pacc = 0.f;
#pragma unroll
    for (int tt = CHSZ - 1; tt >= 0; --tt) {
        int r = c * CHSZ + tt;
        int jj = idxs[base + r];
        float pv = ps[base + r];
        float w = Wh[(base + jj) * 128 + f];
        acc += pv * w;
        accu += w;
        pacc += pv;
        partial[(base + r) * 128 + f] = acc;
        if (f == 0) psuf[base + r] = pacc;
    }
    chunktot[(b * CH + c) * 128 + f] = acc;
    chunku[(b * CH + c) * 128 + f] = accu;
    if (f == 0) chunkp[b * CH + c] = pacc;
}

// ---------------------------------------------------------------------------
// Kernel 4 (MERGED k3b + k4): grid = 256 blocks x 512 threads.
// Block = (batch b = blk>>5, row-group blk&31 -> 64 rows). Steps:
//   1. stage chunktot[b] (64 KB) into LDS cs[][]; reduce chunku -> mean;
//      stage chunkp -> lp.
//   2. 7-step Hillis-Steele inclusive SUFFIX scan of cs over c (tree order,
//      verified round-2) and of lp (scalar).
//   3. per row: lo -> c; exclusive suffix = cs[c+1] (LDS), den = psuf[lo] +
//      lp[c+1]; divide; ELU; store.
// Replaces the 8-block k3b dispatch (3% GPU) + its global chunksuf round-trip.
// ---------------------------------------------------------------------------
__global__ __launch_bounds__(512) void k4_merged(
        const float* __restrict__ chunktot, const float* __restrict__ chunku,
        const float* __restrict__ chunkp,
        const int* __restrict__ lo_arr, const float* __restrict__ psuf,
        const float* __restrict__ partial, float* __restrict__ out) {
    __shared__ __align__(16) float cs[CH][132];   // 67.6 KB, padded (132 % 4 == 0)
    __shared__ __align__(16) float mvp[4][132];
    __shared__ __align__(16) float mv[128];
    __shared__ float lp[CH];
    const int tid = threadIdx.x;
    const int blk = blockIdx.x;
    const int b = blk >> 5;
    const int base = b * NN;

    // ---- stage + partial mean reduce ----
    {
        const int f  = tid & 127;        // fixed per thread
        const int r0 = tid >> 7;         // 0..3
        float su = 0.f;
#pragma unroll 4
        for (int i = 0; i < 32; ++i) {
            int c = r0 + i * 4;
            cs[c][f] = chunktot[(b * CH + c) * 128 + f];
            su += chunku[(b * CH + c) * 128 + f];
        }
        mvp[r0][f] = su;
        if (tid < CH) lp[tid] = chunkp[b * CH + tid];
    }
    __syncthreads();
    if (tid < 128)
        mv[tid] = (mvp[0][tid] + mvp[1][tid] + mvp[2][tid] + mvp[3][tid])
                  * (1.f / (float)NN);

    // ---- tree suffix scans (read-all -> sync -> add-all -> sync) ----
    for (int s = 1; s < CH; s <<= 1) {
        float tmp[32];
#pragma unroll
        for (int i = 0; i < 32; ++i) {
            int c = (tid >> 7) + i * 4;
            int f = tid & 127;
            tmp[i] = (c + s < CH) ? cs[c + s][f] : 0.f;
        }
        float ap = 0.f;
        if (tid < CH && tid + s < CH) ap = lp[tid + s];
        __syncthreads();
#pragma unroll
        for (int i = 0; i < 32; ++i) {
            int c = (tid >> 7) + i * 4;
            int f = tid & 127;
            cs[c][f] += tmp[i];
        }
        if (tid < CH) lp[tid] += ap;
        __syncthreads();
    }
    // cs[c][f] now = inclusive suffix; exclusive at c is cs[c+1] (0 if c==127).

    // ---- combine (row phase, == verified k4 with LDS-resident suffixes) ----
#pragma unroll
    for (int pass = 0; pass < 4; ++pass) {
        const int rowg = blk * 64 + pass * 16 + (tid >> 5);
        const int fq = (tid & 31) * 4;
        const int lo = lo_arr[rowg];
        float4 v;
        if (lo == NN) {
            v = make_float4(mv[fq], mv[fq + 1], mv[fq + 2], mv[fq + 3]);
        } else {
            const int c = lo >> 4;       // / CHSZ
            float4 pp = *(const float4*)&partial[(base + lo) * 128 + fq];
            float4 csv = make_float4(0.f, 0.f, 0.f, 0.f);
            float lps = 0.f;
            if (c < CH - 1) {
                csv = *(const float4*)&cs[c + 1][fq];
                lps = lp[c + 1];
            }
            float den = psuf[base + lo] + lps;
            v.x = (pp.x + csv.x) / den;
            v.y = (pp.y + csv.y) / den;
            v.z = (pp.z + csv.z) / den;
            v.w = (pp.w + csv.w) / den;
        }
        v.x = (v.x > 0.f) ? v.x : expm1f(v.x);
        v.y = (v.y > 0.f) ? v.y : expm1f(v.y);
        v.z = (v.z > 0.f) ? v.z : expm1f(v.z);
        v.w = (v.w > 0.f) ? v.w : expm1f(v.w);
        *(float4*)&out[rowg * 128 + fq] = v;
    }
}

// ---------------------------------------------------------------------------
extern "C" void kernel_launch(void* const* d_in, const int* in_sizes, int n_in,
                              void* d_out, int out_size, void* d_ws, size_t ws_size,
                              hipStream_t stream) {
    (void)in_sizes; (void)n_in; (void)out_size; (void)ws_size;
    const float* h = (const float*)d_in[0];
    const float* W = (const float*)d_in[1];
    const float* a = (const float*)d_in[2];
    // d_in[3]=A1, d_in[4]=A2: dead code in the reference -> never read.
    float* out = (float*)d_out;

    float* Wh       = (float*)d_ws;          // B*N*F = 2,097,152
    float* partial  = Wh + 2097152;          // B*N*F = 2,097,152
    float* s1       = partial + 2097152;     // 16384
    float* s2       = s1 + 16384;
    float* ps       = s2 + 16384;            // 16384
    float* psuf     = ps + 16384;            // 16384
    int*   idxs     = (int*)(psuf + 16384);  // 16384 ints
    int*   lo_arr   = idxs + 16384;          // 16384 ints
    float* chunktot = (float*)(lo_arr + 16384); // B*CH*F = 131072
    float* chunku   = chunktot + 131072;
    float* chunkp   = chunku + 131072;       // B*CH = 1024

    k1_wh<<<BB * NN / 64, 512, 0, stream>>>(h, W, a, Wh, s1, s2);
    k2_rank<<<BB * 32, 512, 0, stream>>>(s2, s1, idxs, ps, lo_arr);
    k3_scan<<<BB * CH, 128, 0, stream>>>(Wh, idxs, ps, partial, psuf,
                                         chunktot, chunku, chunkp);
    k4_merged<<<BB * 32, 512, 0, stream>>>(chunktot, chunku, chunkp,
                                           lo_arr, psuf, partial, out);
}

// Round 4
// 170.032 us; speedup vs baseline: 2.9536x; 1.1067x over previous
//
#include <hip/hip_runtime.h>
#include <math.h>

#define BB 8
#define NN 2048
#define FF 128
#define CH 128        // chunks per batch
#define CHSZ 16       // NN / CH

typedef __attribute__((ext_vector_type(8))) short short8;
typedef __attribute__((ext_vector_type(4))) float f32x4;

__device__ __forceinline__ ushort f2bf(float x) {
    uint u = __float_as_uint(x);
    uint r = (u + 0x7FFFu + ((u >> 16) & 1u)) >> 16;   // round-nearest-even
    return (ushort)r;
}
__device__ __forceinline__ float bf2f(ushort x) {
    return __uint_as_float(((uint)x) << 16);
}

// ---------------------------------------------------------------------------
// Kernel 1 (MFMA): Wh = h @ W^T via bf16 hi/lo split (3 products; lo*lo
// dropped, residual ~2e-5 relative). 256 thr = 4 waves, 64 rows/block,
// each wave: 16 rows x 128 g, K=128 in 4 steps of 32.
// C/D layout (m89-verified): col = lane&15, row = (lane>>4)*4 + reg.
// A/B k-slot mapping cancels between operands (same lane/slot->k map).
// ---------------------------------------------------------------------------
__global__ __launch_bounds__(256) void k1_wh(
        const float* __restrict__ h, const float* __restrict__ W,
        const float* __restrict__ a, float* __restrict__ Wh,
        float* __restrict__ s1, float* __restrict__ s2) {
    __shared__ __align__(16) ushort Whi[128][136];   // 34.8 KB, pad->16B align
    __shared__ __align__(16) ushort Wlo[128][136];
    __shared__ __align__(16) ushort hhi[64][136];
    __shared__ __align__(16) ushort hlo[64][136];
    const int tid = threadIdx.x;
    const int row0 = blockIdx.x * 64;

    // stage W (128x128) -> bf16 hi/lo
    for (int i = tid; i < 4096; i += 256) {
        int g = i >> 5, k4 = (i & 31) * 4;
        float4 wv = *(const float4*)&W[g * 128 + k4];
        ushort h0 = f2bf(wv.x), h1 = f2bf(wv.y), h2 = f2bf(wv.z), h3 = f2bf(wv.w);
        ushort l0 = f2bf(wv.x - bf2f(h0)), l1 = f2bf(wv.y - bf2f(h1));
        ushort l2 = f2bf(wv.z - bf2f(h2)), l3 = f2bf(wv.w - bf2f(h3));
        uint2 hw, lw;
        hw.x = (uint)h0 | ((uint)h1 << 16); hw.y = (uint)h2 | ((uint)h3 << 16);
        lw.x = (uint)l0 | ((uint)l1 << 16); lw.y = (uint)l2 | ((uint)l3 << 16);
        *(uint2*)&Whi[g][k4] = hw;
        *(uint2*)&Wlo[g][k4] = lw;
    }
    // stage h (64x128) -> bf16 hi/lo
    for (int i = tid; i < 2048; i += 256) {
        int r = i >> 5, k4 = (i & 31) * 4;
        float4 hv = *(const float4*)&h[(row0 + r) * 128 + k4];
        ushort h0 = f2bf(hv.x), h1 = f2bf(hv.y), h2 = f2bf(hv.z), h3 = f2bf(hv.w);
        ushort l0 = f2bf(hv.x - bf2f(h0)), l1 = f2bf(hv.y - bf2f(h1));
        ushort l2 = f2bf(hv.z - bf2f(h2)), l3 = f2bf(hv.w - bf2f(h3));
        uint2 hw, lw;
        hw.x = (uint)h0 | ((uint)h1 << 16); hw.y = (uint)h2 | ((uint)h3 << 16);
        lw.x = (uint)l0 | ((uint)l1 << 16); lw.y = (uint)l2 | ((uint)l3 << 16);
        *(uint2*)&hhi[r][k4] = hw;
        *(uint2*)&hlo[r][k4] = lw;
    }
    __syncthreads();

    const int lane = tid & 63;
    const int wid = tid >> 6;            // wave 0..3 -> rows wid*16..+16
    const int gl = lane & 15;            // A-row / B-col within tile
    const int kg = lane >> 4;            // k-group
    const int lr = wid * 16 + gl;        // local A row

    f32x4 acc[8];
#pragma unroll
    for (int gt = 0; gt < 8; ++gt) acc[gt] = (f32x4){0.f, 0.f, 0.f, 0.f};

#pragma unroll
    for (int t = 0; t < 4; ++t) {
        const int k0 = t * 32 + kg * 8;
        short8 ah = *(const short8*)&hhi[lr][k0];
        short8 al = *(const short8*)&hlo[lr][k0];
#pragma unroll
        for (int gt = 0; gt < 8; ++gt) {
            const int g = gt * 16 + gl;
            short8 bh = *(const short8*)&Whi[g][k0];
            short8 bl = *(const short8*)&Wlo[g][k0];
            acc[gt] = __builtin_amdgcn_mfma_f32_16x16x32_bf16(ah, bh, acc[gt], 0, 0, 0);
            acc[gt] = __builtin_amdgcn_mfma_f32_16x16x32_bf16(ah, bl, acc[gt], 0, 0, 0);
            acc[gt] = __builtin_amdgcn_mfma_f32_16x16x32_bf16(al, bh, acc[gt], 0, 0, 0);
        }
    }

    // epilogue: Wh stores + s1/s2 dot products (reduce over the 16 gl lanes)
    float p1a[4] = {0.f, 0.f, 0.f, 0.f}, p2a[4] = {0.f, 0.f, 0.f, 0.f};
#pragma unroll
    for (int gt = 0; gt < 8; ++gt) {
        const int g = gt * 16 + gl;
        const float a1v = a[g];
        const float a2v = a[128 + g];
#pragma unroll
        for (int r = 0; r < 4; ++r) {
            float wvv = acc[gt][r];
            Wh[(row0 + wid * 16 + kg * 4 + r) * 128 + g] = wvv;
            p1a[r] += wvv * a1v;
            p2a[r] += wvv * a2v;
        }
    }
#pragma unroll
    for (int s = 1; s < 16; s <<= 1) {
#pragma unroll
        for (int r = 0; r < 4; ++r) {
            p1a[r] += __shfl_xor(p1a[r], s, 64);
            p2a[r] += __shfl_xor(p2a[r], s, 64);
        }
    }
    if (gl == 0) {
#pragma unroll
        for (int r = 0; r < 4; ++r) {
            int row = row0 + wid * 16 + kg * 4 + r;
            s1[row] = p1a[r];
            s2[row] = p2a[r];
        }
    }
}

// ---------------------------------------------------------------------------
// Kernel 2 (512-thread, verified round 3): stable rank by s2 + exp +
// threshold count. grid = B*32, block = 512. 8 waves each scan 256 keys.
// ---------------------------------------------------------------------------
__global__ __launch_bounds__(512) void k2_rank(
        const float* __restrict__ s2, const float* __restrict__ s1,
        int* __restrict__ idxs, float* __restrict__ ps,
        int* __restrict__ lo_arr) {
    __shared__ __align__(16) float ls[NN];
    __shared__ int part[8][64];
    __shared__ int lpart[8][64];
    __shared__ float wmax[8];
    const int t = threadIdx.x;
    const int blk = blockIdx.x;
    const int b = blk >> 5;              // 32 segs per batch
    const int seg = blk & 31;
    const int base = b * NN;
    float4* ls4 = (float4*)ls;
    const float4* g4 = (const float4*)(s2 + base);
    float m;
    {
        float4 v4 = g4[t];               // 512 float4 = 2048 keys
        ls4[t] = v4;
        m = fmaxf(fmaxf(v4.x, v4.y), fmaxf(v4.z, v4.w));
    }
#pragma unroll
    for (int s = 1; s < 64; s <<= 1) m = fmaxf(m, __shfl_xor(m, s, 64));
    if ((t & 63) == 0) wmax[t >> 6] = m;
    __syncthreads();
    float M = wmax[0];
#pragma unroll
    for (int i = 1; i < 8; ++i) M = fmaxf(M, wmax[i]);
    const int jj = t & 63;
    const int w  = t >> 6;
    const int j  = seg * 64 + jj;        // global j within batch
    const float v = ls[j];
    const float s1v = s1[base + j];
    int rank = 0, cnt = 0;
#pragma unroll 8
    for (int q = 0; q < 64; ++q) {
        float4 kv = ls4[w * 64 + q];     // wave-broadcast, conflict-free
        int kg = w * 256 + q * 4;
        rank += (kv.x < v) | ((kv.x == v) & (kg + 0 < j));
        rank += (kv.y < v) | ((kv.y == v) & (kg + 1 < j));
        rank += (kv.z < v) | ((kv.z == v) & (kg + 2 < j));
        rank += (kv.w < v) | ((kv.w == v) & (kg + 3 < j));
        cnt += (s1v + kv.x <= 0.f);
        cnt += (s1v + kv.y <= 0.f);
        cnt += (s1v + kv.z <= 0.f);
        cnt += (s1v + kv.w <= 0.f);
    }
    part[w][jj] = rank;
    lpart[w][jj] = cnt;
    __syncthreads();
    if (t < 64) {
        int r = 0, lo = 0;
#pragma unroll
        for (int ww = 0; ww < 8; ++ww) {
            r  += part[ww][t];
            lo += lpart[ww][t];
        }
        int jg = seg * 64 + t;
        float vv = ls[jg];
        idxs[base + r] = jg;
        ps[base + r] = expf(vv - M);
        lo_arr[base + jg] = lo;
    }
}

// ---------------------------------------------------------------------------
// Kernel 3 (verified): within-chunk inclusive suffix of p[r]*Wh[idx[r],:]
// (-> partial), p[r] (-> psuf, f==0), plus chunk totals/unweighted sums.
// grid = B*CH blocks, 128 threads (f). Descending accumulation order.
// ---------------------------------------------------------------------------
__global__ __launch_bounds__(128) void k3_scan(
        const float* __restrict__ Wh, const int* __restrict__ idxs,
        const float* __restrict__ ps,
        float* __restrict__ partial, float* __restrict__ psuf,
        float* __restrict__ chunktot, float* __restrict__ chunku,
        float* __restrict__ chunkp) {
    const int blk = blockIdx.x;
    const int b = blk >> 7, c = blk & 127;
    const int base = b * NN;
    const int f = threadIdx.x;
    float acc = 0.f, accu = 0.f, pacc = 0.f;
#pragma unroll
    for (int tt = CHSZ - 1; tt >= 0; --tt) {
        int r = c * CHSZ + tt;
        int jj = idxs[base + r];
        float pv = ps[base + r];
        float w = Wh[(base + jj) * 128 + f];
        acc += pv * w;
        accu += w;
        pacc += pv;
        partial[(base + r) * 128 + f] = acc;
        if (f == 0) psuf[base + r] = pacc;
    }
    chunktot[(b * CH + c) * 128 + f] = acc;
    chunku[(b * CH + c) * 128 + f] = accu;
    if (f == 0) chunkp[b * CH + c] = pacc;
}

// ---------------------------------------------------------------------------
// Kernel 4 v2 (merged k3b+k4, scan restructured): grid = B*32 x 512 thr.
// Thread (q = tid>>7, f = tid&127) owns segment c in [q*32, q*32+32):
//   Phase A: serial suffix over its 32 chunktot values, kept in REGISTERS
//            (global reads, coalesced); chunku summed for the mean.
//   lp suffix: wave 0 via shfl_down suffix scan (2 elems/lane, no extra syncs).
//   Phase C: add 3 upper-segment totals, single LDS write per c.
// LDS ops/thread: ~40 (vs 448 in the Hillis-Steele version).
// Combine phase identical to verified round-3 k4.
// ---------------------------------------------------------------------------
__global__ __launch_bounds__(512) void k4_merged(
        const float* __restrict__ chunktot, const float* __restrict__ chunku,
        const float* __restrict__ chunkp,
        const int* __restrict__ lo_arr, const float* __restrict__ psuf,
        const float* __restrict__ partial, float* __restrict__ out) {
    __shared__ __align__(16) float cs[CH][132];   // 67.6 KB, float4-aligned rows
    __shared__ float segt[4][128];
    __shared__ float mvp[4][128];
    __shared__ float mv[128];
    __shared__ float lp[CH];
    const int tid = threadIdx.x;
    const int blk = blockIdx.x;
    const int b = blk >> 5;
    const int base = b * NN;
    const int f = tid & 127;
    const int q = tid >> 7;              // segment 0..3

    // ---- Phase A: per-thread serial suffix over 32 c's (registers) ----
    float suf[32];
    float acc = 0.f, su = 0.f;
#pragma unroll
    for (int i = 31; i >= 0; --i) {
        int c = q * 32 + i;
        acc += chunktot[(b * CH + c) * 128 + f];
        su  += chunku[(b * CH + c) * 128 + f];
        suf[i] = acc;
    }
    segt[q][f] = acc;
    mvp[q][f] = su;

    // ---- lp (chunkp) suffix scan: wave 0, 2 elems per lane ----
    if (tid < 64) {
        float p0 = chunkp[b * CH + tid * 2];
        float p1v = chunkp[b * CH + tid * 2 + 1];
        float S = p0 + p1v;
        float T = S;
#pragma unroll
        for (int s = 1; s < 64; s <<= 1) {
            float t2 = __shfl_down(T, s, 64);
            if (tid + s < 64) T += t2;
        }
        float E = __shfl_down(T, 1, 64);   // exclusive pair-suffix
        if (tid == 63) E = 0.f;
        lp[tid * 2]     = p0 + p1v + E;
        lp[tid * 2 + 1] = p1v + E;
    }
    __syncthreads();

    // ---- Phase C: segment offsets, write suffix to LDS, mean ----
    float off = 0.f;
#pragma unroll
    for (int qq = 1; qq < 4; ++qq)
        if (q + qq < 4) off += segt[q + qq][f];
#pragma unroll
    for (int i = 0; i < 32; ++i)
        cs[q * 32 + i][f] = suf[i] + off;
    if (tid < 128)
        mv[tid] = (mvp[0][tid] + mvp[1][tid] + mvp[2][tid] + mvp[3][tid])
                  * (1.f / (float)NN);
    __syncthreads();
    // cs[c][f] = inclusive suffix; exclusive at c is cs[c+1] (0 if c==127).

    // ---- combine (verified round-3 logic, LDS-resident suffixes) ----
#pragma unroll
    for (int pass = 0; pass < 4; ++pass) {
        const int rowg = blk * 64 + pass * 16 + (tid >> 5);
        const int fq = (tid & 31) * 4;
        const int lo = lo_arr[rowg];
        float4 v;
        if (lo == NN) {
            v = make_float4(mv[fq], mv[fq + 1], mv[fq + 2], mv[fq + 3]);
        } else {
            const int c = lo >> 4;       // / CHSZ
            float4 pp = *(const float4*)&partial[(base + lo) * 128 + fq];
            float4 csv = make_float4(0.f, 0.f, 0.f, 0.f);
            float lps = 0.f;
            if (c < CH - 1) {
                csv = *(const float4*)&cs[c + 1][fq];
                lps = lp[c + 1];
            }
            float den = psuf[base + lo] + lps;
            v.x = (pp.x + csv.x) / den;
            v.y = (pp.y + csv.y) / den;
            v.z = (pp.z + csv.z) / den;
            v.w = (pp.w + csv.w) / den;
        }
        v.x = (v.x > 0.f) ? v.x : expm1f(v.x);
        v.y = (v.y > 0.f) ? v.y : expm1f(v.y);
        v.z = (v.z > 0.f) ? v.z : expm1f(v.z);
        v.w = (v.w > 0.f) ? v.w : expm1f(v.w);
        *(float4*)&out[rowg * 128 + fq] = v;
    }
}

// ---------------------------------------------------------------------------
extern "C" void kernel_launch(void* const* d_in, const int* in_sizes, int n_in,
                              void* d_out, int out_size, void* d_ws, size_t ws_size,
                              hipStream_t stream) {
    (void)in_sizes; (void)n_in; (void)out_size; (void)ws_size;
    const float* h = (const float*)d_in[0];
    const float* W = (const float*)d_in[1];
    const float* a = (const float*)d_in[2];
    // d_in[3]=A1, d_in[4]=A2: dead code in the reference -> never read.
    float* out = (float*)d_out;

    float* Wh       = (float*)d_ws;          // B*N*F = 2,097,152
    float* partial  = Wh + 2097152;          // B*N*F = 2,097,152
    float* s1       = partial + 2097152;     // 16384
    float* s2       = s1 + 16384;
    float* ps       = s2 + 16384;            // 16384
    float* psuf     = ps + 16384;            // 16384
    int*   idxs     = (int*)(psuf + 16384);  // 16384 ints
    int*   lo_arr   = idxs + 16384;          // 16384 ints
    float* chunktot = (float*)(lo_arr + 16384); // B*CH*F = 131072
    float* chunku   = chunktot + 131072;
    float* chunkp   = chunku + 131072;       // B*CH = 1024

    k1_wh<<<BB * NN / 64, 256, 0, stream>>>(h, W, a, Wh, s1, s2);
    k2_rank<<<BB * 32, 512, 0, stream>>>(s2, s1, idxs, ps, lo_arr);
    k3_scan<<<BB * CH, 128, 0, stream>>>(Wh, idxs, ps, partial, psuf,
                                         chunktot, chunku, chunkp);
    k4_merged<<<BB * 32, 512, 0, stream>>>(chunktot, chunku, chunkp,
                                           lo_arr, psuf, partial, out);
}